// Round 1
// baseline (146.306 us; speedup 1.0000x reference)
//
#include <hip/hip_runtime.h>
#include <hip/hip_bf16.h>

// Problem constants (reference: BATCH=4096, N_VIEWS=2, T=0.07, D=128 -> N=8192)
#define NROWS 8192
#define FDIM  128
#define HALF_N 4096

typedef short bf16x8 __attribute__((ext_vector_type(8)));   // 8 bf16 = 4 VGPRs (guide §3)
typedef float f32x4  __attribute__((ext_vector_type(4)));

// ---------------------------------------------------------------------------
// Kernel 1: L2-normalize rows (fp32 math, matching ref: f / max(||f||, 1e-12)),
// emit bf16 row-major [8192][128]. One wave per row.
// ---------------------------------------------------------------------------
__global__ void __launch_bounds__(64) normalize_kernel(const float* __restrict__ f,
                                                       __hip_bfloat16* __restrict__ out) {
    const int row  = blockIdx.x;
    const int lane = threadIdx.x;           // 0..63, each handles 2 elements
    const float2 v = ((const float2*)(f + row * FDIM))[lane];
    float ss = v.x * v.x + v.y * v.y;
    #pragma unroll
    for (int m = 1; m < 64; m <<= 1) ss += __shfl_xor(ss, m);
    const float scale = 1.0f / fmaxf(sqrtf(ss), 1e-12f);
    __hip_bfloat16* op = out + row * FDIM + lane * 2;
    op[0] = __float2bfloat16(v.x * scale);
    op[1] = __float2bfloat16(v.y * scale);
}

// ---------------------------------------------------------------------------
// Kernel 2: fused sim + exp + row-reduction.
// Grid (64,64): block (bx,by) computes the 128x128 tile rows=by*128.., cols=bx*128..
// of sim = f f^T via mfma_f32_16x16x32_bf16 (full K=128), then accumulates
//   esum_g[i] += sum_{j in tile, j != i} exp((sim_ij - 1)/T)
//   pos_g[i]  += sim_{i, (i+4096)&8191}      (only the one tile that holds it)
// 4 waves = 2x2 quadrants of 64x64; each wave: 4x4 fragments of 16x16.
// Fragment operands load directly from global (2 MB operand, L1/L2 resident).
// ---------------------------------------------------------------------------
__global__ void __launch_bounds__(256) sim_kernel(const short* __restrict__ fn,
                                                  float* __restrict__ esum_g,
                                                  float* __restrict__ pos_g) {
    const int bx   = blockIdx.x;            // col tile
    const int by   = blockIdx.y;            // row tile
    const int tid  = threadIdx.x;
    const int w    = tid >> 6;
    const int lane = tid & 63;
    const int quad = lane >> 4;
    const int l16  = lane & 15;
    const int wrow = (w & 1) * 64;          // wave's row offset within tile
    const int wcol = (w >> 1) * 64;         // wave's col offset within tile
    const int rbase = by * 128 + wrow;
    const int cbase = bx * 128 + wcol;
    const bool is_pos_tile = (bx == ((by + 32) & 63));   // block-uniform

    __shared__ float esum_s[128];
    __shared__ float pos_s[128];
    if (tid < 128) { esum_s[tid] = 0.0f; pos_s[tid] = 0.0f; }
    __syncthreads();

    const bf16x8* fv = (const bf16x8*)fn;

    f32x4 acc[4][4];
    #pragma unroll
    for (int i = 0; i < 4; i++)
        #pragma unroll
        for (int j = 0; j < 4; j++)
            acc[i][j] = (f32x4){0.f, 0.f, 0.f, 0.f};

    // K loop: 4 steps of 32. A-operand layout: row = l16, k = quad*8 + j (m120);
    // B-operand is the symmetric layout, so both frags load identically from f.
    #pragma unroll
    for (int ks = 0; ks < 4; ks++) {
        const int ko = ks * 32 + quad * 8;
        bf16x8 a[4], b[4];
        #pragma unroll
        for (int fr = 0; fr < 4; fr++)
            a[fr] = fv[((rbase + fr * 16 + l16) * FDIM + ko) >> 3];
        #pragma unroll
        for (int fc = 0; fc < 4; fc++)
            b[fc] = fv[((cbase + fc * 16 + l16) * FDIM + ko) >> 3];
        #pragma unroll
        for (int fr = 0; fr < 4; fr++)
            #pragma unroll
            for (int fc = 0; fc < 4; fc++)
                acc[fr][fc] = __builtin_amdgcn_mfma_f32_16x16x32_bf16(
                                  a[fr], b[fc], acc[fr][fc], 0, 0, 0);
    }

    // Epilogue. C/D layout (verified m89/m91): col = l16, row = quad*4 + reg.
    // exp((c-1)/T) = exp2(k1*c - k1), k1 = log2(e)/T.
    const float k1 = 1.4426950408889634f / 0.07f;   // 20.609927...
    #pragma unroll
    for (int fr = 0; fr < 4; fr++) {
        #pragma unroll
        for (int r = 0; r < 4; r++) {
            const int lrow = wrow + fr * 16 + quad * 4 + r;   // row within 128-tile
            const int grow = by * 128 + lrow;
            const int pcol = (grow + HALF_N) & (NROWS - 1);
            float e_acc = 0.0f;
            float p_acc = 0.0f;
            #pragma unroll
            for (int fc = 0; fc < 4; fc++) {
                const int gcol = cbase + fc * 16 + l16;
                const float c  = acc[fr][fc][r];
                float e = exp2f(__builtin_fmaf(c, k1, -k1));
                e = (gcol == grow) ? 0.0f : e;                // drop diagonal
                e_acc += e;
                if (is_pos_tile && gcol == pcol) p_acc += c;  // capture positive
            }
            // reduce across the 16 columns held by lanes sharing this row
            #pragma unroll
            for (int m = 1; m < 16; m <<= 1) e_acc += __shfl_xor(e_acc, m);
            if (is_pos_tile) {
                #pragma unroll
                for (int m = 1; m < 16; m <<= 1) p_acc += __shfl_xor(p_acc, m);
            }
            if (l16 == 0) {
                atomicAdd(&esum_s[lrow], e_acc);
                if (is_pos_tile) atomicAdd(&pos_s[lrow], p_acc);
            }
        }
    }
    __syncthreads();
    if (tid < 128) {
        atomicAdd(&esum_g[by * 128 + tid], esum_s[tid]);
        if (is_pos_tile) atomicAdd(&pos_g[by * 128 + tid], pos_s[tid]);
    }
}

// ---------------------------------------------------------------------------
// Kernel 3: loss_i = ln(esum_i) + 1/T - pos_i/T ; out = mean(loss). One block.
// ---------------------------------------------------------------------------
__global__ void __launch_bounds__(256) final_kernel(const float* __restrict__ esum_g,
                                                    const float* __restrict__ pos_g,
                                                    float* __restrict__ out) {
    const int tid = threadIdx.x;
    const float invT = 1.0f / 0.07f;
    float acc = 0.0f;
    for (int i = tid; i < NROWS; i += 256)
        acc += logf(esum_g[i]) + invT - pos_g[i] * invT;
    #pragma unroll
    for (int m = 1; m < 64; m <<= 1) acc += __shfl_xor(acc, m);
    __shared__ float ws[4];
    if ((tid & 63) == 0) ws[tid >> 6] = acc;
    __syncthreads();
    if (tid == 0) out[0] = (ws[0] + ws[1] + ws[2] + ws[3]) * (1.0f / (float)NROWS);
}

// ---------------------------------------------------------------------------
extern "C" void kernel_launch(void* const* d_in, const int* in_sizes, int n_in,
                              void* d_out, int out_size, void* d_ws, size_t ws_size,
                              hipStream_t stream) {
    const float* features = (const float*)d_in[0];
    float* out = (float*)d_out;

    char* ws = (char*)d_ws;
    __hip_bfloat16* fnorm = (__hip_bfloat16*)ws;                       // 2 MB
    float* esum_g = (float*)(ws + (size_t)NROWS * FDIM * 2);           // 32 KB
    float* pos_g  = (float*)(ws + (size_t)NROWS * FDIM * 2 + NROWS * 4); // 32 KB

    // zero the two row-accumulator arrays (ws is poisoned 0xAA each call)
    hipMemsetAsync(esum_g, 0, (size_t)NROWS * 4 * 2, stream);

    normalize_kernel<<<NROWS, 64, 0, stream>>>(features, fnorm);

    dim3 grid(64, 64);
    sim_kernel<<<grid, 256, 0, stream>>>((const short*)fnorm, esum_g, pos_g);

    final_kernel<<<1, 256, 0, stream>>>(esum_g, pos_g, out);
}

// Round 2
// 124.627 us; speedup vs baseline: 1.1739x; 1.1739x over previous
//
#include <hip/hip_runtime.h>
#include <hip/hip_bf16.h>
#include <cstdint>

// Problem constants (reference: BATCH=4096, N_VIEWS=2, T=0.07, D=128 -> N=8192)
#define NROWS 8192
#define FDIM  128
#define HALF_N 4096

typedef short bf16x8 __attribute__((ext_vector_type(8)));   // 8 bf16 = 4 VGPRs
typedef float f32x4  __attribute__((ext_vector_type(4)));

// Async global->LDS, 16B per lane. LDS dest is wave-uniform base + lane*16
// (m104/m108), so lds ptr must be base + lane-contiguous*16 in lane order.
// AS casts go through uintptr_t (inttoptr — the CK-style spelling): AS(3)
// low-32 truncation of a flat LDS address is the LDS offset on gfx9+.
__device__ __forceinline__ void load16_lds(const void* g, void* l) {
    __builtin_amdgcn_global_load_lds(
        (const __attribute__((address_space(1))) void*)(uintptr_t)g,
        (__attribute__((address_space(3))) void*)(uintptr_t)l,
        16, 0, 0);
}

// ---------------------------------------------------------------------------
// Kernel 1: L2-normalize rows (fp32, matching ref), emit bf16 [8192][128].
// 256-thread blocks, one wave per row. Also zero-inits esum_g/pos_g
// (replaces the hipMemsetAsync graph node).
// ---------------------------------------------------------------------------
__global__ void __launch_bounds__(256) normalize_kernel(const float* __restrict__ f,
                                                        __hip_bfloat16* __restrict__ out,
                                                        float* __restrict__ esum_g,
                                                        float* __restrict__ pos_g) {
    const int row  = blockIdx.x * 4 + (threadIdx.x >> 6);
    const int lane = threadIdx.x & 63;           // each lane: 2 elements
    const float2 v = ((const float2*)(f + (size_t)row * FDIM))[lane];
    float ss = v.x * v.x + v.y * v.y;
    #pragma unroll
    for (int m = 1; m < 64; m <<= 1) ss += __shfl_xor(ss, m);
    const float scale = 1.0f / fmaxf(sqrtf(ss), 1e-12f);
    __hip_bfloat16* op = out + (size_t)row * FDIM + lane * 2;
    op[0] = __float2bfloat16(v.x * scale);
    op[1] = __float2bfloat16(v.y * scale);
    if (threadIdx.x < 4)      esum_g[blockIdx.x * 4 + threadIdx.x] = 0.0f;
    else if (threadIdx.x < 8) pos_g [blockIdx.x * 4 + threadIdx.x - 4] = 0.0f;
}

// ---------------------------------------------------------------------------
// Kernel 2: fused sim + exp + row-reduction, LDS-staged (m97 pattern).
// Grid (64,64): block (bx,by) -> 128x128 tile of sim = f f^T, full K=128.
// Staging: global_load_lds dwordx4 with XOR-swizzled layout:
//   LDS chunk (r, c) <- global chunk (r, c ^ (r & 15))   [16B chunks]
// so fragment ds_read_b128 (16 rows x one chunk column per quad) spreads
// evenly over all 32 banks (8 dwords/bank — conflict-free for b128).
// 4 waves = 2x2 quadrants of 64x64; each wave 4x4 frags of 16x16x32.
// ---------------------------------------------------------------------------
__global__ void __launch_bounds__(256, 2) sim_kernel(const short* __restrict__ fn,
                                                     float* __restrict__ esum_g,
                                                     float* __restrict__ pos_g) {
    __shared__ short As[128 * 128];     // 32 KB
    __shared__ short Bs[128 * 128];     // 32 KB
    __shared__ float esum_s[128];
    __shared__ float pos_s[128];

    const int bx   = blockIdx.x;        // col tile
    const int by   = blockIdx.y;        // row tile
    const int tid  = threadIdx.x;
    const int w    = tid >> 6;
    const int lane = tid & 63;
    const int quad = lane >> 4;
    const int l16  = lane & 15;

    if (tid < 128) { esum_s[tid] = 0.0f; pos_s[tid] = 0.0f; }

    // ---- stage A (rows by*128..) and B (rows bx*128..) tiles, swizzled ----
    // slot = i*256 + tid  ->  r = i*16 + (tid>>4), c_lds = tid&15 (const),
    // c_g = c_lds ^ (r&15) = (tid&15) ^ (tid>>4)  (const across i).
    {
        const int r0 = tid >> 4;                    // 0..15
        const int cg = (tid & 15) ^ r0;             // swizzled global chunk col
        const short* gA = fn + ((size_t)(by * 128 + r0) * FDIM + cg * 8);
        const short* gB = fn + ((size_t)(bx * 128 + r0) * FDIM + cg * 8);
        short* lA = As + tid * 8;
        short* lB = Bs + tid * 8;
        #pragma unroll
        for (int i = 0; i < 8; i++) {
            load16_lds(gA + (size_t)i * 16 * FDIM, lA + i * 2048);
            load16_lds(gB + (size_t)i * 16 * FDIM, lB + i * 2048);
        }
    }
    __syncthreads();   // drains vmcnt(0) for the global_load_lds queue

    const int wrow = (w & 1) * 64;      // wave's row offset within tile
    const int wcol = (w >> 1) * 64;     // wave's col offset within tile
    const bool is_pos_tile = (bx == ((by + 32) & 63));   // block-uniform

    const bf16x8* Av = (const bf16x8*)As;
    const bf16x8* Bv = (const bf16x8*)Bs;

    f32x4 acc[4][4];
    #pragma unroll
    for (int i = 0; i < 4; i++)
        #pragma unroll
        for (int j = 0; j < 4; j++)
            acc[i][j] = (f32x4){0.f, 0.f, 0.f, 0.f};

    // K loop: 4 steps of 32. A layout: row=l16, k=quad*8+j (verified r0 pass).
    // LDS chunk column for (ks,quad) is c0 = ks*4+quad, swizzled by ^l16.
    #pragma unroll
    for (int ks = 0; ks < 4; ks++) {
        const int c0 = ks * 4 + quad;
        bf16x8 a[4], b[4];
        #pragma unroll
        for (int fr = 0; fr < 4; fr++) {
            const int R = wrow + fr * 16 + l16;
            a[fr] = Av[R * 16 + (c0 ^ l16)];
        }
        #pragma unroll
        for (int fc = 0; fc < 4; fc++) {
            const int R = wcol + fc * 16 + l16;
            b[fc] = Bv[R * 16 + (c0 ^ l16)];
        }
        #pragma unroll
        for (int fr = 0; fr < 4; fr++)
            #pragma unroll
            for (int fc = 0; fc < 4; fc++)
                acc[fr][fc] = __builtin_amdgcn_mfma_f32_16x16x32_bf16(
                                  a[fr], b[fc], acc[fr][fc], 0, 0, 0);
    }

    // Epilogue (identical numerics to the round-0 pass). C/D layout:
    // col=l16, row=quad*4+reg. exp((c-1)/T) = exp2(k1*c - k1).
    const float k1 = 1.4426950408889634f / 0.07f;
    #pragma unroll
    for (int fr = 0; fr < 4; fr++) {
        #pragma unroll
        for (int r = 0; r < 4; r++) {
            const int lrow = wrow + fr * 16 + quad * 4 + r;   // row within tile
            const int grow = by * 128 + lrow;
            const int pcol = (grow + HALF_N) & (NROWS - 1);
            float e_acc = 0.0f;
            float p_acc = 0.0f;
            #pragma unroll
            for (int fc = 0; fc < 4; fc++) {
                const int gcol = bx * 128 + wcol + fc * 16 + l16;
                const float c  = acc[fr][fc][r];
                float e = exp2f(__builtin_fmaf(c, k1, -k1));
                e = (gcol == grow) ? 0.0f : e;                // drop diagonal
                e_acc += e;
                if (is_pos_tile && gcol == pcol) p_acc += c;  // capture positive
            }
            #pragma unroll
            for (int m = 1; m < 16; m <<= 1) e_acc += __shfl_xor(e_acc, m);
            if (is_pos_tile) {
                #pragma unroll
                for (int m = 1; m < 16; m <<= 1) p_acc += __shfl_xor(p_acc, m);
            }
            if (l16 == 0) {
                atomicAdd(&esum_s[lrow], e_acc);
                if (is_pos_tile) atomicAdd(&pos_s[lrow], p_acc);
            }
        }
    }
    __syncthreads();
    if (tid < 128) {
        atomicAdd(&esum_g[by * 128 + tid], esum_s[tid]);
        if (is_pos_tile) atomicAdd(&pos_g[by * 128 + tid], pos_s[tid]);
    }
}

// ---------------------------------------------------------------------------
// Kernel 3: loss_i = ln(esum_i) + 1/T - pos_i/T ; out = mean(loss). One block.
// ---------------------------------------------------------------------------
__global__ void __launch_bounds__(256) final_kernel(const float* __restrict__ esum_g,
                                                    const float* __restrict__ pos_g,
                                                    float* __restrict__ out) {
    const int tid = threadIdx.x;
    const float invT = 1.0f / 0.07f;
    float acc = 0.0f;
    for (int i = tid; i < NROWS; i += 256)
        acc += logf(esum_g[i]) + invT - pos_g[i] * invT;
    #pragma unroll
    for (int m = 1; m < 64; m <<= 1) acc += __shfl_xor(acc, m);
    __shared__ float ws[4];
    if ((tid & 63) == 0) ws[tid >> 6] = acc;
    __syncthreads();
    if (tid == 0) out[0] = (ws[0] + ws[1] + ws[2] + ws[3]) * (1.0f / (float)NROWS);
}

// ---------------------------------------------------------------------------
extern "C" void kernel_launch(void* const* d_in, const int* in_sizes, int n_in,
                              void* d_out, int out_size, void* d_ws, size_t ws_size,
                              hipStream_t stream) {
    const float* features = (const float*)d_in[0];
    float* out = (float*)d_out;

    char* ws = (char*)d_ws;
    __hip_bfloat16* fnorm = (__hip_bfloat16*)ws;                         // 2 MB
    float* esum_g = (float*)(ws + (size_t)NROWS * FDIM * 2);             // 32 KB
    float* pos_g  = (float*)(ws + (size_t)NROWS * FDIM * 2 + NROWS * 4); // 32 KB

    normalize_kernel<<<NROWS / 4, 256, 0, stream>>>(features, fnorm, esum_g, pos_g);

    dim3 grid(64, 64);
    sim_kernel<<<grid, 256, 0, stream>>>((const short*)fnorm, esum_g, pos_g);

    final_kernel<<<1, 256, 0, stream>>>(esum_g, pos_g, out);
}

// Round 3
// 99.917 us; speedup vs baseline: 1.4643x; 1.2473x over previous
//
#include <hip/hip_runtime.h>
#include <hip/hip_bf16.h>
#include <cstdint>

// Problem constants (reference: BATCH=4096, N_VIEWS=2, T=0.07, D=128 -> N=8192)
#define NROWS 8192
#define FDIM  128
#define HALF_N 4096

typedef short bf16x8 __attribute__((ext_vector_type(8)));   // 8 bf16 = 4 VGPRs
typedef float f32x4  __attribute__((ext_vector_type(4)));

// Async global->LDS, 16B per lane; LDS dest must be wave-uniform base + lane*16.
__device__ __forceinline__ void load16_lds(const void* g, void* l) {
    __builtin_amdgcn_global_load_lds(
        (const __attribute__((address_space(1))) void*)(uintptr_t)g,
        (__attribute__((address_space(3))) void*)(uintptr_t)l,
        16, 0, 0);
}

// Stage one 128x128 bf16 tile (global rows start at g) into a 32 KB LDS buffer
// with the XOR-16 chunk swizzle: LDS chunk (r,c) <- global chunk (r, c^(r&15)).
// Verified conflict-free in round 2 (SQ_LDS_BANK_CONFLICT = 0).
__device__ __forceinline__ void stage_tile(const short* __restrict__ g,
                                           short* l, int tid) {
    const int r0 = tid >> 4;                 // 0..15
    const int sc = (tid & 15) ^ r0;          // swizzled global chunk col
    const short* gp = g + (size_t)r0 * FDIM + sc * 8;
    short* lp = l + tid * 8;
    #pragma unroll
    for (int i = 0; i < 8; i++)
        load16_lds(gp + (size_t)i * 16 * FDIM, lp + i * 2048);
}

// ---------------------------------------------------------------------------
// Kernel 1: L2-normalize rows (fp32, matching ref), emit bf16 [8192][128].
// Also zero-inits esum_g / pos_g.
// ---------------------------------------------------------------------------
__global__ void __launch_bounds__(256) normalize_kernel(const float* __restrict__ f,
                                                        __hip_bfloat16* __restrict__ out,
                                                        float* __restrict__ esum_g,
                                                        float* __restrict__ pos_g) {
    const int row  = blockIdx.x * 4 + (threadIdx.x >> 6);
    const int lane = threadIdx.x & 63;
    const float2 v = ((const float2*)(f + (size_t)row * FDIM))[lane];
    float ss = v.x * v.x + v.y * v.y;
    #pragma unroll
    for (int m = 1; m < 64; m <<= 1) ss += __shfl_xor(ss, m);
    const float scale = 1.0f / fmaxf(sqrtf(ss), 1e-12f);
    __hip_bfloat16* op = out + (size_t)row * FDIM + lane * 2;
    op[0] = __float2bfloat16(v.x * scale);
    op[1] = __float2bfloat16(v.y * scale);
    if (threadIdx.x < 4)      esum_g[blockIdx.x * 4 + threadIdx.x] = 0.0f;
    else if (threadIdx.x < 8) pos_g [blockIdx.x * 4 + threadIdx.x - 4] = 0.0f;
}

// ---------------------------------------------------------------------------
// Kernel 2: persistent-strip fused sim+exp+rowsum.
// Grid 512 = 64 row-strips x 8 col-groups. Block (by,cg): rows by*128..+128,
// B-tiles bx = cg*8 .. cg*8+7. A-tile staged once -> registers (a_reg[4][4],
// 64 VGPR). B-tiles double-buffered in LDS; stage of tile t+1 issued before
// compute of tile t so the end-of-tile barrier drain is ~free. Row-sums of
// exp((s-1)/T) accumulate in registers (ep[4][4]) across all 8 tiles; one
// shuffle-reduce + global atomicAdd per row at the end.
// ---------------------------------------------------------------------------
__global__ void __launch_bounds__(256, 2) sim_kernel(const short* __restrict__ fn,
                                                     float* __restrict__ esum_g,
                                                     float* __restrict__ pos_g) {
    __shared__ short buf0[128 * 128];   // 32 KB
    __shared__ short buf1[128 * 128];   // 32 KB

    const int by   = blockIdx.x >> 3;   // row strip
    const int cg   = blockIdx.x & 7;    // col group
    const int tid  = threadIdx.x;
    const int w    = tid >> 6;
    const int lane = tid & 63;
    const int quad = lane >> 4;
    const int l16  = lane & 15;
    const int wrow = (w & 1) * 64;      // wave's row offset within strip
    const int wcol = (w >> 1) * 64;     // wave's col offset within tile

    // ---- prologue: stage A -> buf1, B0 -> buf0 ----
    stage_tile(fn + (size_t)(by * 128) * FDIM, buf1, tid);
    stage_tile(fn + (size_t)(cg * 8 * 128) * FDIM, buf0, tid);
    __syncthreads();

    // A fragments to registers: a_reg[ks][fr]; A layout row=l16, k=quad*8+j.
    bf16x8 a_reg[4][4];
    {
        const bf16x8* Av = (const bf16x8*)buf1;
        #pragma unroll
        for (int ks = 0; ks < 4; ks++)
            #pragma unroll
            for (int fr = 0; fr < 4; fr++)
                a_reg[ks][fr] = Av[(wrow + fr * 16 + l16) * 16 + ((ks * 4 + quad) ^ l16)];
    }
    __syncthreads();   // all waves done reading A before buf1 is re-staged (t=0)

    float ep[4][4];    // [fr][r] per-lane row partials (16 rows this lane touches)
    #pragma unroll
    for (int i = 0; i < 4; i++)
        #pragma unroll
        for (int j = 0; j < 4; j++)
            ep[i][j] = 0.0f;

    const float k1 = 1.4426950408889634f / 0.07f;   // log2(e)/T
    const int pos_bx = (by + 32) & 63;

    for (int t = 0; t < 8; t++) {
        const int bx = cg * 8 + t;
        short* cur = (t & 1) ? buf1 : buf0;
        short* nxt = (t & 1) ? buf0 : buf1;
        if (t < 7)
            stage_tile(fn + (size_t)((bx + 1) * 128) * FDIM, nxt, tid);

        f32x4 acc[4][4];
        #pragma unroll
        for (int i = 0; i < 4; i++)
            #pragma unroll
            for (int j = 0; j < 4; j++)
                acc[i][j] = (f32x4){0.f, 0.f, 0.f, 0.f};

        const bf16x8* Bv = (const bf16x8*)cur;
        #pragma unroll
        for (int ks = 0; ks < 4; ks++) {
            bf16x8 b[4];
            #pragma unroll
            for (int fc = 0; fc < 4; fc++)
                b[fc] = Bv[(wcol + fc * 16 + l16) * 16 + ((ks * 4 + quad) ^ l16)];
            #pragma unroll
            for (int fr = 0; fr < 4; fr++)
                #pragma unroll
                for (int fc = 0; fc < 4; fc++)
                    acc[fr][fc] = __builtin_amdgcn_mfma_f32_16x16x32_bf16(
                                      a_reg[ks][fr], b[fc], acc[fr][fc], 0, 0, 0);
        }

        // ---- epilogue: accumulate exp into register row partials ----
        // C/D layout: col = l16 (within 16-col frag), row = quad*4 + r.
        if (bx == by) {          // block-uniform: the diagonal tile
            #pragma unroll
            for (int fr = 0; fr < 4; fr++)
                #pragma unroll
                for (int r = 0; r < 4; r++) {
                    const int lrow = wrow + fr * 16 + quad * 4 + r;
                    #pragma unroll
                    for (int fc = 0; fc < 4; fc++) {
                        const int lcol = wcol + fc * 16 + l16;
                        float e = exp2f(__builtin_fmaf(acc[fr][fc][r], k1, -k1));
                        e = (lcol == lrow) ? 0.0f : e;   // drop diagonal
                        ep[fr][r] += e;
                    }
                }
        } else {
            #pragma unroll
            for (int fr = 0; fr < 4; fr++)
                #pragma unroll
                for (int r = 0; r < 4; r++)
                    #pragma unroll
                    for (int fc = 0; fc < 4; fc++)
                        ep[fr][r] += exp2f(__builtin_fmaf(acc[fr][fc][r], k1, -k1));
        }

        // positive capture: pos col of global row g is g+4096 mod 8192, which
        // lands in tile bx == (by+32)&63 at local col == local row. Only the
        // waves with wrow==wcol can see it.
        if (bx == pos_bx && wrow == wcol) {
            #pragma unroll
            for (int fr = 0; fr < 4; fr++)
                #pragma unroll
                for (int r = 0; r < 4; r++) {
                    const int lrow = wrow + fr * 16 + quad * 4 + r;
                    float p = 0.0f;
                    #pragma unroll
                    for (int fc = 0; fc < 4; fc++) {
                        const int lcol = wcol + fc * 16 + l16;
                        p += (lcol == lrow) ? acc[fr][fc][r] : 0.0f;
                    }
                    #pragma unroll
                    for (int m = 1; m < 16; m <<= 1) p += __shfl_xor(p, m);
                    if (l16 == 0) atomicAdd(&pos_g[by * 128 + lrow], p);
                }
        }

        __syncthreads();   // drains nxt staging; guards cur overwrite at t+1
    }

    // ---- once per block: reduce register row partials, commit to global ----
    #pragma unroll
    for (int fr = 0; fr < 4; fr++)
        #pragma unroll
        for (int r = 0; r < 4; r++) {
            float v = ep[fr][r];
            #pragma unroll
            for (int m = 1; m < 16; m <<= 1) v += __shfl_xor(v, m);
            if (l16 == 0)
                atomicAdd(&esum_g[by * 128 + wrow + fr * 16 + quad * 4 + r], v);
        }
}

// ---------------------------------------------------------------------------
// Kernel 3: loss_i = ln(esum_i) + 1/T - pos_i/T ; out = mean(loss). One block.
// ---------------------------------------------------------------------------
__global__ void __launch_bounds__(256) final_kernel(const float* __restrict__ esum_g,
                                                    const float* __restrict__ pos_g,
                                                    float* __restrict__ out) {
    const int tid = threadIdx.x;
    const float invT = 1.0f / 0.07f;
    float acc = 0.0f;
    for (int i = tid; i < NROWS; i += 256)
        acc += logf(esum_g[i]) + invT - pos_g[i] * invT;
    #pragma unroll
    for (int m = 1; m < 64; m <<= 1) acc += __shfl_xor(acc, m);
    __shared__ float ws[4];
    if ((tid & 63) == 0) ws[tid >> 6] = acc;
    __syncthreads();
    if (tid == 0) out[0] = (ws[0] + ws[1] + ws[2] + ws[3]) * (1.0f / (float)NROWS);
}

// ---------------------------------------------------------------------------
extern "C" void kernel_launch(void* const* d_in, const int* in_sizes, int n_in,
                              void* d_out, int out_size, void* d_ws, size_t ws_size,
                              hipStream_t stream) {
    const float* features = (const float*)d_in[0];
    float* out = (float*)d_out;

    char* ws = (char*)d_ws;
    __hip_bfloat16* fnorm = (__hip_bfloat16*)ws;                         // 2 MB
    float* esum_g = (float*)(ws + (size_t)NROWS * FDIM * 2);             // 32 KB
    float* pos_g  = (float*)(ws + (size_t)NROWS * FDIM * 2 + NROWS * 4); // 32 KB

    normalize_kernel<<<NROWS / 4, 256, 0, stream>>>(features, fnorm, esum_g, pos_g);

    sim_kernel<<<512, 256, 0, stream>>>((const short*)fnorm, esum_g, pos_g);

    final_kernel<<<1, 256, 0, stream>>>(esum_g, pos_g, out);
}

// Round 4
// 94.368 us; speedup vs baseline: 1.5504x; 1.0588x over previous
//
#include <hip/hip_runtime.h>
#include <hip/hip_bf16.h>
#include <cstdint>

// Problem constants (reference: BATCH=4096, N_VIEWS=2, T=0.07, D=128 -> N=8192)
#define NROWS 8192
#define FDIM  128
#define HALF_N 4096

typedef short bf16x8 __attribute__((ext_vector_type(8)));   // 8 bf16 = 4 VGPRs
typedef float f32x4  __attribute__((ext_vector_type(4)));

// k1 = log2(e)/T so exp((s-1)/T) = exp2(k1*s - k1)
#define K1 (1.4426950408889634f / 0.07f)

// Fragment-packed layout of the normalized bf16 matrix:
//   P[rowblock rb][ks][lane] : bf16x8, lane = quad*16 + (r&15),
//   holding row r = rb*16+(lane&15), k = ks*32 + quad*8 .. +8.
// This IS the MFMA A/B operand register image — a wave loads a fragment with
// ONE coalesced global_load_dwordx4 (lane i -> base + 16*i). 2 MB total.
// flat bf16x8 index of frag (rb, ks) = (rb*4 + ks)*64 + lane.

// ---------------------------------------------------------------------------
// Kernel 1: L2-normalize rows (fp32, matching ref), write fragment-packed
// bf16. Also zero-inits esum_g.
// ---------------------------------------------------------------------------
__global__ void __launch_bounds__(256) normalize_kernel(const float* __restrict__ f,
                                                        short* __restrict__ packed,
                                                        float* __restrict__ esum_g) {
    const int row  = blockIdx.x * 4 + (threadIdx.x >> 6);
    const int lane = threadIdx.x & 63;           // element k = 2*lane, 2*lane+1
    const float2 v = ((const float2*)(f + (size_t)row * FDIM))[lane];
    float ss = v.x * v.x + v.y * v.y;
    #pragma unroll
    for (int m = 1; m < 64; m <<= 1) ss += __shfl_xor(ss, m);
    const float scale = 1.0f / fmaxf(sqrtf(ss), 1e-12f);

    // packed position of (row, k=2*lane): ks = lane>>4, quad = (lane>>2)&3,
    // within-chunk elem = 2*(lane&3)
    const int off = ((((row >> 4) * 4 + (lane >> 4)) * 64)
                     + ((lane >> 2) & 3) * 16 + (row & 15)) * 8 + 2 * (lane & 3);
    __hip_bfloat16 b0 = __float2bfloat16(v.x * scale);
    __hip_bfloat16 b1 = __float2bfloat16(v.y * scale);
    unsigned u = (unsigned)*(unsigned short*)&b0
               | ((unsigned)*(unsigned short*)&b1 << 16);
    *(unsigned*)(packed + off) = u;              // 4B-aligned (off is even)

    if (threadIdx.x < 4) esum_g[blockIdx.x * 4 + threadIdx.x] = 0.0f;
}

__device__ __forceinline__ float2 bf2_to_f2(unsigned u) {
    return make_float2(__uint_as_float(u << 16),
                       __uint_as_float(u & 0xffff0000u));
}

// ---------------------------------------------------------------------------
// Kernel 2: barrier-free fused sim+exp+rowsum.
// Blocks 0..511: 4 waves each, wave g = b*4+w owns rows strip*64..+64
// (strip = g>>4) x cols j*512..+512 (j = g&15). A-frags parked in 64 VGPRs;
// B-frags streamed register-ping-pong from packed global (L2-resident,
// coalesced). No LDS, no __syncthreads -> no vmcnt(0) drains.
// esum includes the diagonal term (subtracted in final via diag_g).
// Blocks 512..543: one thread per row i: pos_i = <f_i, f_(i^4096)>,
// diag_i = exp2(K1*<f_i,f_i> - K1)  (bf16-quantized, fp32 accumulate).
// ---------------------------------------------------------------------------
__global__ void __launch_bounds__(256, 3) sim_kernel(const short* __restrict__ pk,
                                                     float* __restrict__ esum_g,
                                                     float* __restrict__ pos_g,
                                                     float* __restrict__ diag_g) {
    if (blockIdx.x >= 512) {
        // ---- pos/diag path: one thread per row ----
        const int i  = (blockIdx.x - 512) * 256 + threadIdx.x;
        const int ip = i ^ HALF_N;
        const uint4* P = (const uint4*)pk;
        float dot = 0.f, self = 0.f;
        #pragma unroll
        for (int c = 0; c < 16; c++) {           // c = ks*4 + quad
            const uint4 a = P[((i  >> 4) * 4 + (c >> 2)) * 64 + (c & 3) * 16 + (i  & 15)];
            const uint4 b = P[((ip >> 4) * 4 + (c >> 2)) * 64 + (c & 3) * 16 + (ip & 15)];
            const unsigned au[4] = {a.x, a.y, a.z, a.w};
            const unsigned bu[4] = {b.x, b.y, b.z, b.w};
            #pragma unroll
            for (int q = 0; q < 4; q++) {
                const float2 av = bf2_to_f2(au[q]);
                const float2 bv = bf2_to_f2(bu[q]);
                dot  = __builtin_fmaf(av.x, bv.x, __builtin_fmaf(av.y, bv.y, dot));
                self = __builtin_fmaf(av.x, av.x, __builtin_fmaf(av.y, av.y, self));
            }
        }
        pos_g[i]  = dot;
        diag_g[i] = exp2f(__builtin_fmaf(self, K1, -K1));
        return;
    }

    const int tid   = threadIdx.x;
    const int w     = tid >> 6;
    const int lane  = tid & 63;
    const int gw    = blockIdx.x * 4 + w;
    const int strip = gw >> 4;                   // 0..127: rows strip*64..+64
    const int j     = gw & 15;                   // cols j*512..+512
    const bf16x8* P = (const bf16x8*)pk;

    // A fragments for this wave's 64 rows: a_reg[ks][fr]
    bf16x8 a_reg[4][4];
    #pragma unroll
    for (int fr = 0; fr < 4; fr++)
        #pragma unroll
        for (int ks = 0; ks < 4; ks++)
            a_reg[ks][fr] = P[((strip * 4 + fr) * 4 + ks) * 64 + lane];

    float ep[4][4];                              // [fr][r] row partials
    #pragma unroll
    for (int a = 0; a < 4; a++)
        #pragma unroll
        for (int b = 0; b < 4; b++) ep[a][b] = 0.0f;

    const int cb0 = j * 32;                      // first global colblock
    bf16x8 b0[4], b1[4];
    #pragma unroll
    for (int ks = 0; ks < 4; ks++)
        b0[ks] = P[(cb0 * 4 + ks) * 64 + lane];

#define COMPUTE(BF)                                                          \
    {                                                                        \
        f32x4 acc[4];                                                        \
        _Pragma("unroll")                                                    \
        for (int fr = 0; fr < 4; fr++) acc[fr] = (f32x4){0.f, 0.f, 0.f, 0.f};\
        _Pragma("unroll")                                                    \
        for (int ks = 0; ks < 4; ks++)                                       \
            _Pragma("unroll")                                                \
            for (int fr = 0; fr < 4; fr++)                                   \
                acc[fr] = __builtin_amdgcn_mfma_f32_16x16x32_bf16(           \
                              a_reg[ks][fr], BF[ks], acc[fr], 0, 0, 0);      \
        _Pragma("unroll")                                                    \
        for (int fr = 0; fr < 4; fr++)                                       \
            _Pragma("unroll")                                                \
            for (int r = 0; r < 4; r++)                                      \
                ep[fr][r] += exp2f(__builtin_fmaf(acc[fr][r], K1, -K1));     \
    }

    for (int cb = 0; cb < 32; cb += 2) {
        #pragma unroll
        for (int ks = 0; ks < 4; ks++)
            b1[ks] = P[((cb0 + cb + 1) * 4 + ks) * 64 + lane];
        COMPUTE(b0);
        if (cb + 2 < 32) {
            #pragma unroll
            for (int ks = 0; ks < 4; ks++)
                b0[ks] = P[((cb0 + cb + 2) * 4 + ks) * 64 + lane];
        }
        COMPUTE(b1);
    }
#undef COMPUTE

    // reduce row partials across the 16 column-lanes, commit once per wave
    #pragma unroll
    for (int fr = 0; fr < 4; fr++)
        #pragma unroll
        for (int r = 0; r < 4; r++) {
            float v = ep[fr][r];
            #pragma unroll
            for (int m = 1; m < 16; m <<= 1) v += __shfl_xor(v, m);
            if ((lane & 15) == 0)
                atomicAdd(&esum_g[strip * 64 + fr * 16 + (lane >> 4) * 4 + r], v);
        }
}

// ---------------------------------------------------------------------------
// Kernel 3: loss_i = ln(esum_i - diag_i) + 1/T - pos_i/T ; out = mean(loss).
// ---------------------------------------------------------------------------
__global__ void __launch_bounds__(256) final_kernel(const float* __restrict__ esum_g,
                                                    const float* __restrict__ pos_g,
                                                    const float* __restrict__ diag_g,
                                                    float* __restrict__ out) {
    const int tid = threadIdx.x;
    const float invT = 1.0f / 0.07f;
    float acc = 0.0f;
    for (int i = tid; i < NROWS; i += 256)
        acc += logf(esum_g[i] - diag_g[i]) + invT - pos_g[i] * invT;
    #pragma unroll
    for (int m = 1; m < 64; m <<= 1) acc += __shfl_xor(acc, m);
    __shared__ float ws[4];
    if ((tid & 63) == 0) ws[tid >> 6] = acc;
    __syncthreads();
    if (tid == 0) out[0] = (ws[0] + ws[1] + ws[2] + ws[3]) * (1.0f / (float)NROWS);
}

// ---------------------------------------------------------------------------
extern "C" void kernel_launch(void* const* d_in, const int* in_sizes, int n_in,
                              void* d_out, int out_size, void* d_ws, size_t ws_size,
                              hipStream_t stream) {
    const float* features = (const float*)d_in[0];
    float* out = (float*)d_out;

    char* ws = (char*)d_ws;
    short* packed = (short*)ws;                                          // 2 MB
    float* esum_g = (float*)(ws + (size_t)NROWS * FDIM * 2);             // 32 KB
    float* pos_g  = (float*)(ws + (size_t)NROWS * FDIM * 2 + NROWS * 4); // 32 KB
    float* diag_g = (float*)(ws + (size_t)NROWS * FDIM * 2 + NROWS * 8); // 32 KB

    normalize_kernel<<<NROWS / 4, 256, 0, stream>>>(features, packed, esum_g);

    sim_kernel<<<512 + NROWS / 256, 256, 0, stream>>>(packed, esum_g, pos_g, diag_g);

    final_kernel<<<1, 256, 0, stream>>>(esum_g, pos_g, diag_g, out);
}

// Round 5
// 89.162 us; speedup vs baseline: 1.6409x; 1.0584x over previous
//
#include <hip/hip_runtime.h>
#include <hip/hip_bf16.h>
#include <cstdint>

// Problem constants (reference: BATCH=4096, N_VIEWS=2, T=0.07, D=128 -> N=8192)
#define NROWS 8192
#define FDIM  128
#define HALF_N 4096

typedef short bf16x8 __attribute__((ext_vector_type(8)));   // 8 bf16 = 4 VGPRs
typedef float f32x4  __attribute__((ext_vector_type(4)));

// k1 = log2(e)/T so exp((s-1)/T) = exp2(k1*s - k1)
#define K1 (1.4426950408889634f / 0.07f)

#if __has_builtin(__builtin_amdgcn_exp2f)
#define EXP2(x) __builtin_amdgcn_exp2f(x)       // raw v_exp_f32
#else
#define EXP2(x) exp2f(x)
#endif

// Fragment-packed layout of the normalized bf16 matrix:
//   frag (rb, ks) at flat bf16x8 index (rb*4+ks)*64 + lane,
//   lane = quad*16 + (r&15) holds row r = rb*16+(lane&15), k = ks*32+quad*8..+8.
// This IS the MFMA A/B operand register image — one coalesced
// global_load_dwordx4 per fragment. 2 MB total.

// ---------------------------------------------------------------------------
// Kernel 1: L2-normalize rows (fp32, matching ref), write fragment-packed
// bf16. Also zero-inits esum_g.
// ---------------------------------------------------------------------------
__global__ void __launch_bounds__(256) normalize_kernel(const float* __restrict__ f,
                                                        short* __restrict__ packed,
                                                        float* __restrict__ esum_g) {
    const int row  = blockIdx.x * 4 + (threadIdx.x >> 6);
    const int lane = threadIdx.x & 63;           // element k = 2*lane, 2*lane+1
    const float2 v = ((const float2*)(f + (size_t)row * FDIM))[lane];
    float ss = v.x * v.x + v.y * v.y;
    #pragma unroll
    for (int m = 1; m < 64; m <<= 1) ss += __shfl_xor(ss, m);
    const float scale = 1.0f / fmaxf(sqrtf(ss), 1e-12f);

    // packed position of (row, k=2*lane): ks = lane>>4, quad = (lane>>2)&3
    const int off = ((((row >> 4) * 4 + (lane >> 4)) * 64)
                     + ((lane >> 2) & 3) * 16 + (row & 15)) * 8 + 2 * (lane & 3);
    __hip_bfloat16 b0 = __float2bfloat16(v.x * scale);
    __hip_bfloat16 b1 = __float2bfloat16(v.y * scale);
    unsigned u = (unsigned)*(unsigned short*)&b0
               | ((unsigned)*(unsigned short*)&b1 << 16);
    *(unsigned*)(packed + off) = u;              // 4B-aligned (off is even)

    if (threadIdx.x < 4) esum_g[blockIdx.x * 4 + threadIdx.x] = 0.0f;
}

__device__ __forceinline__ float2 bf2_to_f2(unsigned u) {
    return make_float2(__uint_as_float(u << 16),
                       __uint_as_float(u & 0xffff0000u));
}

// ---------------------------------------------------------------------------
// Kernel 2: barrier-free fused sim+exp+rowsum.
// Blocks 0..511: j = blockIdx&15 (col group, SHARED by the block's 4 waves so
// their B-fragment streams alias in L1 — 4x less L2 traffic, L1-hit latency),
// strip = (blockIdx>>4)*4 + w (each wave its own 64 rows). A-frags parked in
// 64 VGPRs; B-frags register ping-pong. No LDS, no __syncthreads.
// esum includes the diagonal term (subtracted in final via diag_g).
// Blocks 512..543: one thread per row i: pos_i = <f_i, f_(i^4096)>,
// diag_i = exp2(K1*<f_i,f_i> - K1)  (bf16-quantized, fp32 accumulate).
// ---------------------------------------------------------------------------
__global__ void __launch_bounds__(256, 3) sim_kernel(const short* __restrict__ pk,
                                                     float* __restrict__ esum_g,
                                                     float* __restrict__ pos_g,
                                                     float* __restrict__ diag_g) {
    if (blockIdx.x >= 512) {
        // ---- pos/diag path: one thread per row ----
        const int i  = (blockIdx.x - 512) * 256 + threadIdx.x;
        const int ip = i ^ HALF_N;
        const uint4* P = (const uint4*)pk;
        float dot = 0.f, self = 0.f;
        #pragma unroll
        for (int c = 0; c < 16; c++) {           // c = ks*4 + quad
            const uint4 a = P[((i  >> 4) * 4 + (c >> 2)) * 64 + (c & 3) * 16 + (i  & 15)];
            const uint4 b = P[((ip >> 4) * 4 + (c >> 2)) * 64 + (c & 3) * 16 + (ip & 15)];
            const unsigned au[4] = {a.x, a.y, a.z, a.w};
            const unsigned bu[4] = {b.x, b.y, b.z, b.w};
            #pragma unroll
            for (int q = 0; q < 4; q++) {
                const float2 av = bf2_to_f2(au[q]);
                const float2 bv = bf2_to_f2(bu[q]);
                dot  = __builtin_fmaf(av.x, bv.x, __builtin_fmaf(av.y, bv.y, dot));
                self = __builtin_fmaf(av.x, av.x, __builtin_fmaf(av.y, av.y, self));
            }
        }
        pos_g[i]  = dot;
        diag_g[i] = EXP2(__builtin_fmaf(self, K1, -K1));
        return;
    }

    const int tid   = threadIdx.x;
    const int w     = tid >> 6;
    const int lane  = tid & 63;
    const int j     = blockIdx.x & 15;           // col group: SHARED in block
    const int strip = (blockIdx.x >> 4) * 4 + w; // 0..127: rows strip*64..+64
    const bf16x8* P = (const bf16x8*)pk;

    // A fragments for this wave's 64 rows: a_reg[ks][fr]
    bf16x8 a_reg[4][4];
    #pragma unroll
    for (int fr = 0; fr < 4; fr++)
        #pragma unroll
        for (int ks = 0; ks < 4; ks++)
            a_reg[ks][fr] = P[((strip * 4 + fr) * 4 + ks) * 64 + lane];

    float ep[4][4];                              // [fr][r] row partials
    #pragma unroll
    for (int a = 0; a < 4; a++)
        #pragma unroll
        for (int b = 0; b < 4; b++) ep[a][b] = 0.0f;

    const int cb0 = j * 32;                      // first global colblock
    bf16x8 b0[4], b1[4];
    #pragma unroll
    for (int ks = 0; ks < 4; ks++)
        b0[ks] = P[(cb0 * 4 + ks) * 64 + lane];

#define COMPUTE(BF)                                                          \
    {                                                                        \
        f32x4 acc[4];                                                        \
        _Pragma("unroll")                                                    \
        for (int fr = 0; fr < 4; fr++) acc[fr] = (f32x4){0.f, 0.f, 0.f, 0.f};\
        _Pragma("unroll")                                                    \
        for (int ks = 0; ks < 4; ks++)                                       \
            _Pragma("unroll")                                                \
            for (int fr = 0; fr < 4; fr++)                                   \
                acc[fr] = __builtin_amdgcn_mfma_f32_16x16x32_bf16(           \
                              a_reg[ks][fr], BF[ks], acc[fr], 0, 0, 0);      \
        _Pragma("unroll")                                                    \
        for (int fr = 0; fr < 4; fr++)                                       \
            _Pragma("unroll")                                                \
            for (int r = 0; r < 4; r++)                                      \
                ep[fr][r] += EXP2(__builtin_fmaf(acc[fr][r], K1, -K1));      \
    }

    for (int cb = 0; cb < 32; cb += 2) {
        #pragma unroll
        for (int ks = 0; ks < 4; ks++)
            b1[ks] = P[((cb0 + cb + 1) * 4 + ks) * 64 + lane];
        COMPUTE(b0);
        if (cb + 2 < 32) {
            #pragma unroll
            for (int ks = 0; ks < 4; ks++)
                b0[ks] = P[((cb0 + cb + 2) * 4 + ks) * 64 + lane];
        }
        COMPUTE(b1);
    }
#undef COMPUTE

    // reduce row partials across the 16 column-lanes, commit once per wave
    #pragma unroll
    for (int fr = 0; fr < 4; fr++)
        #pragma unroll
        for (int r = 0; r < 4; r++) {
            float v = ep[fr][r];
            #pragma unroll
            for (int m = 1; m < 16; m <<= 1) v += __shfl_xor(v, m);
            if ((lane & 15) == 0)
                atomicAdd(&esum_g[strip * 64 + fr * 16 + (lane >> 4) * 4 + r], v);
        }
}

// ---------------------------------------------------------------------------
// Kernel 3: loss_i = ln(esum_i - diag_i) + 1/T - pos_i/T ; out = mean(loss).
// ---------------------------------------------------------------------------
__global__ void __launch_bounds__(256) final_kernel(const float* __restrict__ esum_g,
                                                    const float* __restrict__ pos_g,
                                                    const float* __restrict__ diag_g,
                                                    float* __restrict__ out) {
    const int tid = threadIdx.x;
    const float invT = 1.0f / 0.07f;
    float acc = 0.0f;
    for (int i = tid; i < NROWS; i += 256)
        acc += logf(esum_g[i] - diag_g[i]) + invT - pos_g[i] * invT;
    #pragma unroll
    for (int m = 1; m < 64; m <<= 1) acc += __shfl_xor(acc, m);
    __shared__ float ws[4];
    if ((tid & 63) == 0) ws[tid >> 6] = acc;
    __syncthreads();
    if (tid == 0) out[0] = (ws[0] + ws[1] + ws[2] + ws[3]) * (1.0f / (float)NROWS);
}

// ---------------------------------------------------------------------------
extern "C" void kernel_launch(void* const* d_in, const int* in_sizes, int n_in,
                              void* d_out, int out_size, void* d_ws, size_t ws_size,
                              hipStream_t stream) {
    const float* features = (const float*)d_in[0];
    float* out = (float*)d_out;

    char* ws = (char*)d_ws;
    short* packed = (short*)ws;                                          // 2 MB
    float* esum_g = (float*)(ws + (size_t)NROWS * FDIM * 2);             // 32 KB
    float* pos_g  = (float*)(ws + (size_t)NROWS * FDIM * 2 + NROWS * 4); // 32 KB
    float* diag_g = (float*)(ws + (size_t)NROWS * FDIM * 2 + NROWS * 8); // 32 KB

    normalize_kernel<<<NROWS / 4, 256, 0, stream>>>(features, packed, esum_g);

    sim_kernel<<<512 + NROWS / 256, 256, 0, stream>>>(packed, esum_g, pos_g, diag_g);

    final_kernel<<<1, 256, 0, stream>>>(esum_g, pos_g, diag_g, out);
}